// Round 1
// 161.276 us; speedup vs baseline: 1.0008x; 1.0008x over previous
//
#include <hip/hip_runtime.h>
#include <hip/hip_bf16.h>

#define IPB 4  // images per block; one wave per image, waves fully independent

// Dequant factors: f32 weak-casts of the Python f64 scale chain (proven R11).
constexpr double dDQ1 = 0.05 * 0.05;
constexpr double dDQ2 = 0.05 * 0.05 * 16.0 * 0.05;
constexpr double dDQ3 = 0.05 * 0.05 * 16.0 * 0.05 * 16.0 * 0.05;
constexpr double dDQ4 = 0.05 * 0.05 * 16.0 * 0.05 * 16.0 * 0.05 * 16.0 * 0.05;

// XLA algebraic-simplifier reciprocals: f32(1 / f32(scale_k)) (proven R11).
#define R1f 20.0f
#define R2f 25.0f
#define R3f 31.2499980926513671875f
#define R4f 39.0625f

#if __has_builtin(__builtin_amdgcn_sdot4)
__device__ __forceinline__ int dot4(int a, int b, int c) {
    return __builtin_amdgcn_sdot4(a, b, c, false);
}
#else
__device__ __forceinline__ int dot4(int a, int b, int c) {
    #pragma unroll
    for (int k = 0; k < 4; ++k)
        c += (int)(signed char)(a >> (8 * k)) * (int)(signed char)(b >> (8 * k));
    return c;
}
#endif

// pack byte sel of a dword from a non-negative integral float (exact: value
// is integral in [0,127] after rintf, so f32->u8 trunc == round, clamp dead).
__device__ __forceinline__ unsigned pk_u8(float f, unsigned sel, unsigned old) {
#if __has_builtin(__builtin_amdgcn_cvt_pk_u8_f32)
    return __builtin_amdgcn_cvt_pk_u8_f32(f, sel, old);
#else
    return old | (((unsigned)(int)f & 0xffu) << (8u * sel));
#endif
}

// wave-local LDS ordering: s_waitcnt lgkmcnt(0) + compiler fence, NO s_barrier.
// All LDS buffers are wave-private (slot-indexed); intra-wave DS ops are
// in-order and the waitcnt drains them — block waves stay decoupled.
__device__ __forceinline__ void wave_fence() {
    __builtin_amdgcn_fence(__ATOMIC_ACQ_REL, "workgroup");
}

// Round f32 -> nearest bf16 (RNE), return as f32 (golden's final cast).
__device__ __forceinline__ float bfr(float f) {
    unsigned int u = __builtin_bit_cast(unsigned int, f);
    u += 0x7fffu + ((u >> 16) & 1u);
    u &= 0xffff0000u;
    return __builtin_bit_cast(float, u);
}

// quantize 4 input pixels (x in [0,1) => t = rint(20x) in [0,20], no clamp needed)
__device__ __forceinline__ int packq(float4 v) {
    unsigned r = pk_u8(rintf(v.x * R1f), 0u, 0u);
    r = pk_u8(rintf(v.y * R1f), 1u, r);
    r = pk_u8(rintf(v.z * R1f), 2u, r);
    r = pk_u8(rintf(v.w * R1f), 3u, r);
    return (int)r;
}

// ---- prep kernel: pack integer weights as char4 dwords into d_ws ----
__global__ void qcnn_prep(const float* __restrict__ w1, const float* __restrict__ w2,
                          const float* __restrict__ w3, const float* __restrict__ w4,
                          int* __restrict__ wpk) {
    int t = threadIdx.x;
    if (t < 24) {
        int oc = t / 6, rem = t % 6, r = rem >> 1, sh = rem & 1;
        int v = 0;
        #pragma unroll
        for (int k = 0; k < 4; ++k) {
            int kw = k - sh;
            int w = (kw >= 0 && kw < 3) ? (int)w1[(r * 3 + kw) * 16 + oc] : 0;
            v |= (w & 0xff) << (8 * k);
        }
        wpk[t] = v;
    } else if (t < 60) {
        int e = t - 24, tap = e >> 2, oc = e & 3, v = 0;
        #pragma unroll
        for (int k = 0; k < 4; ++k) v |= (((int)w2[tap * 16 + k * 4 + oc]) & 0xff) << (8 * k);
        wpk[t] = v;
    } else if (t < 96) {
        int e = t - 60, tap = e >> 2, oc = e & 3, v = 0;
        #pragma unroll
        for (int k = 0; k < 4; ++k) v |= (((int)w3[tap * 16 + k * 4 + oc]) & 0xff) << (8 * k);
        wpk[t] = v;
    } else if (t < 108) {
        int col = t - 96, v = 0;
        #pragma unroll
        for (int k = 0; k < 4; ++k) v |= (((int)w4[k * 12 + col]) & 0xff) << (8 * k);
        wpk[t] = v;
    }
}

__global__ __launch_bounds__(256, 8) void qcnn_main(
    const float* __restrict__ x,
    const int* __restrict__ wpk,
    float* __restrict__ out, int B)
{
    // q1a rows are 7 dwords (28 cols); padded to 200 dwords/slot so the
    // speculative pair-read bp[r*7+1] (max index 196) stays in-bounds.
    __shared__ int q1a[IPB][200];   // 28 rows x 7 dwords (cols 4j..4j+3)
    __shared__ int q2c[IPB][169];   // 13x13 cells, char4 over oc
    __shared__ int q3c[IPB][25];    // 5x5 cells, char4 over oc

    const int tid = threadIdx.x, slot = tid >> 6, lane = tid & 63;
    const int img = blockIdx.x * IPB + slot;
    const bool valid = img < B;
    const float DQ1 = (float)dDQ1, DQ2 = (float)dDQ2, DQ3 = (float)dDQ3, DQ4 = (float)dDQ4;

    // ---- S0: quantize input; front-load the 3-4 global reads (vmcnt overlap) ----
    if (valid) {
        const float4* x4 = (const float4*)(x + (size_t)img * 784);
        float4 v0 = x4[lane];
        float4 v1 = x4[lane + 64];
        float4 v2 = x4[lane + 128];
        float4 v3 = (lane < 4) ? x4[lane + 192] : make_float4(0.f, 0.f, 0.f, 0.f);
        q1a[slot][lane]       = packq(v0);
        q1a[slot][lane + 64]  = packq(v1);
        q1a[slot][lane + 128] = packq(v2);
        if (lane < 4) q1a[slot][lane + 192] = packq(v3);
    }
    wave_fence();

    // ---- S1: conv1 -> pool2x2 -> relu -> requant : q2c[169] ----
    // odd-aligned windows handled in-register: read dword pair, funnel-shift
    // by 16 (v_alignbit) and select — replaces the old shifted q1b LDS copy.
    if (valid) {
        int W1[24];
        #pragma unroll
        for (int i = 0; i < 24; ++i) W1[i] = wpk[i];
        #pragma unroll
        for (int it = 0; it < 3; ++it) {
            int cell = lane + 64 * it;
            if (cell < 169) {
                int ph = cell / 13, pw = cell - ph * 13;
                int r0 = 2 * ph, c0 = 2 * pw;
                bool odd = (c0 & 2) != 0;
                const int* bp = &q1a[slot][r0 * 7 + (c0 >> 2)];
                int rw[4];
                #pragma unroll
                for (int r = 0; r < 4; ++r) {
                    int a = bp[r * 7], b = bp[r * 7 + 1];   // ds_read2_b32 pair
                    int sh = (int)(((unsigned)a >> 16) | ((unsigned)b << 16));
                    rw[r] = odd ? sh : a;
                }
                unsigned outb = 0;
                #pragma unroll
                for (int oc = 0; oc < 4; ++oc) {
                    int a00 = 0, a01 = 0, a10 = 0, a11 = 0;
                    #pragma unroll
                    for (int r = 0; r < 3; ++r) {
                        a00 = dot4(rw[r],     W1[oc * 6 + r * 2 + 0], a00);
                        a01 = dot4(rw[r],     W1[oc * 6 + r * 2 + 1], a01);
                        a10 = dot4(rw[r + 1], W1[oc * 6 + r * 2 + 0], a10);
                        a11 = dot4(rw[r + 1], W1[oc * 6 + r * 2 + 1], a11);
                    }
                    int m = max(max(a00, a01), max(a10, a11));  // pool raw int accs
                    float y = fmaxf((float)m * DQ1, 0.f);       // dequant+relu
                    // t = rint(y*25) <= rint(3.6*25) = 90 < 127: clamp dead
                    outb = pk_u8(rintf(y * R2f), (unsigned)oc, outb);
                }
                q2c[slot][cell] = (int)outb;
            }
        }
    }
    wave_fence();

    // ---- S2: conv2 -> pool2x2 (shfl over pos-quad) -> relu -> requant : q3c[25] ----
    {
        int W2[36];
        #pragma unroll
        for (int i = 0; i < 36; ++i) W2[i] = wpk[24 + i];
        #pragma unroll
        for (int base_it = 0; base_it < 128; base_it += 64) {
            int it = base_it + lane;
            int a0 = 0, a1 = 0, a2 = 0, a3 = 0;
            int cell = 0, pos = 0;
            bool act = valid && it < 100;
            if (act) {
                cell = it >> 2; pos = it & 3;
                int ph = cell / 5, pw = cell - ph * 5;
                int ib = (2 * ph + (pos >> 1)) * 13 + 2 * pw + (pos & 1);
                const int* p = &q2c[slot][ib];
                #pragma unroll
                for (int kh = 0; kh < 3; ++kh)
                    #pragma unroll
                    for (int kw = 0; kw < 3; ++kw) {
                        int d = p[kh * 13 + kw];
                        a0 = dot4(d, W2[(kh * 3 + kw) * 4 + 0], a0);
                        a1 = dot4(d, W2[(kh * 3 + kw) * 4 + 1], a1);
                        a2 = dot4(d, W2[(kh * 3 + kw) * 4 + 2], a2);
                        a3 = dot4(d, W2[(kh * 3 + kw) * 4 + 3], a3);
                    }
            }
            int m0 = a0, m1 = a1, m2 = a2, m3 = a3;
            m0 = max(m0, __shfl_xor(m0, 1)); m0 = max(m0, __shfl_xor(m0, 2));
            m1 = max(m1, __shfl_xor(m1, 1)); m1 = max(m1, __shfl_xor(m1, 2));
            m2 = max(m2, __shfl_xor(m2, 1)); m2 = max(m2, __shfl_xor(m2, 2));
            m3 = max(m3, __shfl_xor(m3, 1)); m3 = max(m3, __shfl_xor(m3, 2));
            if (act && pos == 0) {
                unsigned outb = 0;
                int mm[4] = {m0, m1, m2, m3};
                #pragma unroll
                for (int oc = 0; oc < 4; ++oc) {
                    float y = fmaxf((float)mm[oc] * DQ2, 0.f);
                    float t = fminf(rintf(y * R3f), 127.f);     // clamp needed here
                    outb = pk_u8(t, (unsigned)oc, outb);
                }
                q3c[slot][cell] = (int)outb;
            }
        }
    }
    wave_fence();

    // ---- S3+S3b+S4 fused, all cross-lane via shfl (no LDS, no fences) ----
    // conv3 raw accs live in lanes pos*4+oc (pos=0..8); inactive lanes hold
    // INT_MIN so the xor-tree max over the 16-lane stride-4 group yields the
    // 3x3-pooled max for oc=lane&3 in EVERY lane.
    int a3 = (int)0x80000000u;
    if (valid && lane < 36) {
        int oc = lane & 3, pos = lane >> 2;
        int oh = pos / 3, ow = pos - oh * 3;
        const int* p = &q3c[slot][oh * 5 + ow];
        a3 = 0;
        #pragma unroll
        for (int kh = 0; kh < 3; ++kh)
            #pragma unroll
            for (int kw = 0; kw < 3; ++kw)
                a3 = dot4(p[kh * 5 + kw], wpk[60 + (kh * 3 + kw) * 4 + oc], a3);
    }
    #pragma unroll
    for (int s = 4; s <= 32; s <<= 1) a3 = max(a3, __shfl_xor(a3, s));
    // pool3x3 -> relu -> requant (redundantly in all lanes; exact)
    float y3 = fmaxf((float)a3 * DQ3, 0.f);
    float t3 = fminf(rintf(y3 * R4f), 127.f);                   // clamp needed
    int b4 = (int)pk_u8(t3, (unsigned)(lane & 3), 0u);
    b4 |= __shfl_xor(b4, 1);
    b4 |= __shfl_xor(b4, 2);
    // conv4 (1x1, 4->12, keep 10) -> dequant -> relu -> bf16-grid store
    if (valid && lane < 10) {
        int a4 = dot4(b4, wpk[96 + lane], 0);
        float y = fmaxf((float)a4 * DQ4, 0.f);
        out[(size_t)img * 10 + lane] = bfr(y);
    }
}

extern "C" void kernel_launch(void* const* d_in, const int* in_sizes, int n_in,
                              void* d_out, int out_size, void* d_ws, size_t ws_size,
                              hipStream_t stream) {
    (void)n_in; (void)ws_size; (void)out_size;
    const float* x  = (const float*)d_in[0];
    const float* w1 = (const float*)d_in[1];
    const float* w2 = (const float*)d_in[2];
    const float* w3 = (const float*)d_in[3];
    const float* w4 = (const float*)d_in[4];
    int* wpk = (int*)d_ws;
    float* out = (float*)d_out;

    const int B = in_sizes[0] / 784;
    qcnn_prep<<<1, 128, 0, stream>>>(w1, w2, w3, w4, wpk);
    qcnn_main<<<(B + IPB - 1) / IPB, 256, 0, stream>>>(x, wpk, out, B);
}